// Round 8
// baseline (5629.031 us; speedup 1.0000x reference)
//
#include <hip/hip_runtime.h>
#include <hip/hip_bf16.h>
#include <stdint.h>
#include <stddef.h>

#define E_ 8
#define C_ 4096
#define H_ 1024
#define I_ 4096

typedef short s16;
typedef __attribute__((ext_vector_type(8))) short short8;   // 8 bf16 (4 VGPRs)
typedef __attribute__((ext_vector_type(4))) short short4v;  // 4 bf16 (8B)
typedef __attribute__((ext_vector_type(4))) float f32x4;    // MFMA C/D frag
typedef __attribute__((ext_vector_type(4))) float float4v;

__device__ __forceinline__ s16 f2bf(float f) {
  union { __hip_bfloat16 h; s16 s; } u;
  u.h = __float2bfloat16(f);
  return u.s;
}

// async global->LDS, 16B per lane. LDS dest is wave-uniform base + lane*16.
__device__ __forceinline__ void gload16(const void* gsrc, void* ldst) {
  __builtin_amdgcn_global_load_lds(
      (const __attribute__((address_space(1))) void*)gsrc,
      (__attribute__((address_space(3))) void*)ldst, 16, 0, 0);
}

// ---------------------------------------------------------------------------
// prep: expert = blockIdx.y   (unchanged from r3..r7)
// z=0: x fp32 -> bf16
// z=1: Wg [H][I] -> interleaved Wgu rows (gate block)   [2I][H] bf16
// z=2: Wu [H][I] -> interleaved Wgu rows (up block)
// z=3: Wd [I][H] -> WdT [H][I] bf16
// ---------------------------------------------------------------------------
__global__ __launch_bounds__(256) void prep_kernel(
    const float* __restrict__ x, const float* __restrict__ Wg,
    const float* __restrict__ Wu, const float* __restrict__ Wd,
    s16* __restrict__ xb, s16* __restrict__ Wgu, s16* __restrict__ WdT)
{
  __shared__ float tile[64][65];
  const int t = threadIdx.x;
  const int z = blockIdx.z;
  const size_t e = blockIdx.y;

  if (z == 0) {
    size_t base = e * (size_t)C_ * H_ + ((size_t)blockIdx.x * 256 + t) * 16;
    for (int j = 0; j < 16; j += 8) {
      float4v v0 = *(const float4v*)(x + base + j);
      float4v v1 = *(const float4v*)(x + base + j + 4);
      s16 o[8];
      o[0] = f2bf(v0[0]); o[1] = f2bf(v0[1]); o[2] = f2bf(v0[2]); o[3] = f2bf(v0[3]);
      o[4] = f2bf(v1[0]); o[5] = f2bf(v1[1]); o[6] = f2bf(v1[2]); o[7] = f2bf(v1[3]);
      *(short8*)(xb + base + j) = *(short8*)o;
    }
    return;
  }

  const float* src; int Cc;
  if (z == 1)      { src = Wg + e * (size_t)H_ * I_; Cc = I_; }
  else if (z == 2) { src = Wu + e * (size_t)H_ * I_; Cc = I_; }
  else             { src = Wd + e * (size_t)H_ * I_; Cc = H_; }

  const int tpr  = Cc >> 6;
  const int trow = blockIdx.x / tpr;
  const int tcol = blockIdx.x % tpr;

  const int c = t & 63, rq = t >> 6;
  for (int i = 0; i < 16; ++i) {
    int r = rq * 16 + i;
    tile[r][c] = src[(size_t)(trow * 64 + r) * Cc + tcol * 64 + c];
  }
  __syncthreads();

  const int ro = t >> 2, cb = (t & 3) * 16;
  s16 o[16];
  for (int j = 0; j < 16; ++j) o[j] = f2bf(tile[cb + j][ro]);

  const int i0 = tcol * 64 + ro;   // transposed row index
  s16* op;
  if (z == 3) {
    op = WdT + e * (size_t)H_ * I_ + (size_t)i0 * I_ + trow * 64 + cb;
  } else {
    int grow = ((i0 & ~15) << 1) + (i0 & 15) + ((z == 2) ? 16 : 0);
    op = Wgu + e * (size_t)2 * I_ * H_ + (size_t)grow * H_ + trow * 64 + cb;
  }
  *(short8*)op       = *(short8*)&o[0];
  *(short8*)(op + 8) = *(short8*)&o[8];
}

// ===========================================================================
// Shared MFMA macro (swapped operands -> D^T layout, r7-verified):
// lane holds row = base + m*16 + (lane&15), cols n*16 + (lane>>4)*4 + q.
// ===========================================================================
#define MFMA16(MH, A0, A1, A2, A3)                                                            \
  acc[(MH)*4+0][0] = __builtin_amdgcn_mfma_f32_16x16x32_bf16(bf[0], A0, acc[(MH)*4+0][0],0,0,0); \
  acc[(MH)*4+0][1] = __builtin_amdgcn_mfma_f32_16x16x32_bf16(bf[1], A0, acc[(MH)*4+0][1],0,0,0); \
  acc[(MH)*4+0][2] = __builtin_amdgcn_mfma_f32_16x16x32_bf16(bf[2], A0, acc[(MH)*4+0][2],0,0,0); \
  acc[(MH)*4+0][3] = __builtin_amdgcn_mfma_f32_16x16x32_bf16(bf[3], A0, acc[(MH)*4+0][3],0,0,0); \
  acc[(MH)*4+1][0] = __builtin_amdgcn_mfma_f32_16x16x32_bf16(bf[0], A1, acc[(MH)*4+1][0],0,0,0); \
  acc[(MH)*4+1][1] = __builtin_amdgcn_mfma_f32_16x16x32_bf16(bf[1], A1, acc[(MH)*4+1][1],0,0,0); \
  acc[(MH)*4+1][2] = __builtin_amdgcn_mfma_f32_16x16x32_bf16(bf[2], A1, acc[(MH)*4+1][2],0,0,0); \
  acc[(MH)*4+1][3] = __builtin_amdgcn_mfma_f32_16x16x32_bf16(bf[3], A1, acc[(MH)*4+1][3],0,0,0); \
  acc[(MH)*4+2][0] = __builtin_amdgcn_mfma_f32_16x16x32_bf16(bf[0], A2, acc[(MH)*4+2][0],0,0,0); \
  acc[(MH)*4+2][1] = __builtin_amdgcn_mfma_f32_16x16x32_bf16(bf[1], A2, acc[(MH)*4+2][1],0,0,0); \
  acc[(MH)*4+2][2] = __builtin_amdgcn_mfma_f32_16x16x32_bf16(bf[2], A2, acc[(MH)*4+2][2],0,0,0); \
  acc[(MH)*4+2][3] = __builtin_amdgcn_mfma_f32_16x16x32_bf16(bf[3], A2, acc[(MH)*4+2][3],0,0,0); \
  acc[(MH)*4+3][0] = __builtin_amdgcn_mfma_f32_16x16x32_bf16(bf[0], A3, acc[(MH)*4+3][0],0,0,0); \
  acc[(MH)*4+3][1] = __builtin_amdgcn_mfma_f32_16x16x32_bf16(bf[1], A3, acc[(MH)*4+3][1],0,0,0); \
  acc[(MH)*4+3][2] = __builtin_amdgcn_mfma_f32_16x16x32_bf16(bf[2], A3, acc[(MH)*4+3][2],0,0,0); \
  acc[(MH)*4+3][3] = __builtin_amdgcn_mfma_f32_16x16x32_bf16(bf[3], A3, acc[(MH)*4+3][3],0,0,0);

#define VMW0 asm volatile("s_waitcnt vmcnt(0)" ::: "memory");
#define VMW4 asm volatile("s_waitcnt vmcnt(4)" ::: "memory");

// ===========================================================================
// gemm_gu: gateup, 256x256 tile, BK=32, 64 KiB LDS -> 2 blocks/CU.
// Folded LDS layout per 16KB tile: logical [256][32] stored as [128][64],
// physical elem(R,c) = (R>>1)*64 + (((R&1)*32 + c) ^ (((R>>1)&7)<<3)).
// 4 phases per 2-K-tile iteration; stage t+1->b1 @ph1, t+2->b0 @ph3;
// vmcnt(0) at ph2/ph4-end publishes before the consuming barrier.
// ===========================================================================
#define LDA32(B, MH, M) \
  (*(const short8*)(shm + (B)*8192 + aBase + (MH)*2048 + (M)*512))
#define LDB32(B, N) \
  (*(const short8*)(shm + 16384 + (B)*8192 + bBase + (N)*512))

#define PH32(B, MH, TOPSTMT, TAILSTMT)                                       \
  {                                                                          \
    TOPSTMT                                                                  \
    short8 af0 = LDA32(B, MH, 0);                                            \
    short8 af1 = LDA32(B, MH, 1);                                            \
    short8 af2 = LDA32(B, MH, 2);                                            \
    short8 af3 = LDA32(B, MH, 3);                                            \
    __builtin_amdgcn_sched_barrier(0);                                       \
    __builtin_amdgcn_s_barrier();                                            \
    asm volatile("s_waitcnt lgkmcnt(0)" ::: "memory");                       \
    __builtin_amdgcn_sched_barrier(0);                                       \
    __builtin_amdgcn_s_setprio(1);                                           \
    MFMA16(MH, af0, af1, af2, af3)                                           \
    __builtin_amdgcn_s_setprio(0);                                           \
    __builtin_amdgcn_sched_barrier(0);                                       \
    TAILSTMT                                                                 \
    __builtin_amdgcn_s_barrier();                                            \
  }

__global__ __launch_bounds__(512, 4) void gemm_gu(
    const s16* __restrict__ Abase, const s16* __restrict__ Bbase,
    s16* __restrict__ HOut)
{
  constexpr int K   = H_;          // 1024
  constexpr int NB  = 2 * I_;      // 8192
  constexpr int NT  = K / 32;      // 32 K-tiles
  constexpr int TN  = NB / 256;    // 32

  __shared__ s16 shm[32768];       // 64 KiB: A [2][8192] | B [2][8192]

  const int tid  = threadIdx.x;
  const int wave = tid >> 6, lane = tid & 63;
  const int e    = blockIdx.z;

  // fetch-optimal per-XCD partition (r4): 8bn x 8bm per XCD, bn-inner.
  const int bid = blockIdx.x;
  const int xcd = bid & 7;
  const int idx = bid >> 3;
  const int bn = (xcd & 3) * 8 + (idx & 7);
  const int bm = (xcd >> 2) * 8 + (idx >> 3);

  const s16* A = Abase + (size_t)e * C_ * K + (size_t)bm * 256 * K;
  const s16* B = Bbase + (size_t)e * NB * K + (size_t)bn * 256 * K;

  const int wm  = (wave >> 2) * 128;
  const int wn  = (wave & 3) * 64;
  const int lr  = lane & 15;
  const int lkb = (lane >> 4) * 8;

  // read-side folded-swizzle constants (verified round-trip vs staging)
  const int qA    = (((lr & 1) << 5) | lkb) ^ ((lr >> 1) << 3);
  const int aBase = (wm << 5) + ((lr >> 1) << 6) + qA;
  const int bBase = (wn << 5) + ((lr >> 1) << 6) + qA;

  // staging constants: lane l writes physical (P=(i*8+w)*8 + (l>>3), q8=(l&7)*8)
  const int l      = lane;
  const int inner  = (((l & 7) ^ (l >> 3)) << 3);
  const int rloc   = ((l >> 3) << 1) | (inner >> 5);
  const int ck     = inner & 31;
  const int sdst   = wave * 512;   // elems; + i*4096

  auto stageA = [&](int kt, int b) {
    #pragma unroll
    for (int i = 0; i < 2; ++i)
      gload16(A + (size_t)(i * 128 + wave * 16 + rloc) * K + kt * 32 + ck,
              shm + b * 8192 + i * 4096 + sdst);
  };
  auto stageB = [&](int kt, int b) {
    #pragma unroll
    for (int i = 0; i < 2; ++i)
      gload16(B + (size_t)(i * 128 + wave * 16 + rloc) * K + kt * 32 + ck,
              shm + 16384 + b * 8192 + i * 4096 + sdst);
  };

  f32x4 acc[8][4];
  #pragma unroll
  for (int m = 0; m < 8; ++m)
    #pragma unroll
    for (int n = 0; n < 4; ++n) acc[m][n] = (f32x4){0.f, 0.f, 0.f, 0.f};

  // prologue: tile0 -> b0
  stageA(0, 0);
  stageB(0, 0);
  VMW0
  __builtin_amdgcn_sched_barrier(0);
  __builtin_amdgcn_s_barrier();

  short8 bf[4];
  // iteration i computes (t=2i -> b0, t+1 -> b1).
  // ph1: stage t+1->b1 (b1's old content last read prev ph4, published by its
  //      closing barrier); ph3: stage t+2->b0 (b0 last read ph2, published).
  // VMW0 at ph2/ph4-end publishes staged tile before consuming barrier.
  for (int i = 0; i < NT / 2; ++i) {
    const int t1 = 2 * i + 1;
    const int t2 = (2 * i + 2 < NT) ? (2 * i + 2) : (NT - 1);
    PH32(0, 0,
         { stageA(t1, 1); stageB(t1, 1);
           bf[0] = LDB32(0, 0); bf[1] = LDB32(0, 1);
           bf[2] = LDB32(0, 2); bf[3] = LDB32(0, 3); }, )
    PH32(0, 1, {}, VMW0)
    PH32(1, 0,
         { stageA(t2, 0); stageB(t2, 0);
           bf[0] = LDB32(1, 0); bf[1] = LDB32(1, 1);
           bf[2] = LDB32(1, 2); bf[3] = LDB32(1, 3); }, )
    PH32(1, 1, {}, VMW0)
  }

  // epilogue (D^T layout, r7-verified), non-temporal stores (keep L3 for
  // weights: hbf write-stream must not thrash it).
  const int lcc = (lane >> 4) * 4;
  s16* Hp = HOut + (size_t)e * C_ * I_;
  const int ibase = bn * 128 + (wn >> 1);
  #pragma unroll
  for (int m = 0; m < 8; ++m) {
    const int row = bm * 256 + wm + m * 16 + lr;
    #pragma unroll
    for (int p = 0; p < 2; ++p) {
      const int col = ibase + p * 16 + lcc;
      s16 o4[4];
      #pragma unroll
      for (int q = 0; q < 4; ++q) {
        float g = acc[m][2 * p][q], u = acc[m][2 * p + 1][q];
        float sg = 1.0f / (1.0f + __expf(-g));
        o4[q] = f2bf(g * sg * u);
      }
      __builtin_nontemporal_store(*(short4v*)o4,
                                  (short4v*)(Hp + (size_t)row * I_ + col));
    }
  }
}

// ===========================================================================
// gemm_dn: down GEMM — r7 structure FROZEN (control), + nt final stores.
// 256x256 tile, BK=64, 8-phase, 128 KiB LDS, 1 block/CU.
// ===========================================================================
#define LDAF(B, MH, M, CX) \
  (*(const short8*)(shm + (B)*16384 + ((wm + (MH)*64 + (M)*16 + lr) << 6) + (CX)))
#define LDBF(B, N, CX) \
  (*(const short8*)(shm + 32768 + (B)*16384 + ((wn + (N)*16 + lr) << 6) + (CX)))

#define PHASE(B, MH, CX, RDB, STMT, WV)                                      \
  {                                                                          \
    short8 af0 = LDAF(B, MH, 0, CX);                                         \
    short8 af1 = LDAF(B, MH, 1, CX);                                         \
    short8 af2 = LDAF(B, MH, 2, CX);                                         \
    short8 af3 = LDAF(B, MH, 3, CX);                                         \
    if (RDB) {                                                               \
      bf[0] = LDBF(B, 0, CX); bf[1] = LDBF(B, 1, CX);                        \
      bf[2] = LDBF(B, 2, CX); bf[3] = LDBF(B, 3, CX);                        \
    }                                                                        \
    STMT                                                                     \
    __builtin_amdgcn_sched_barrier(0);                                       \
    __builtin_amdgcn_s_barrier();                                            \
    asm volatile("s_waitcnt lgkmcnt(0)" ::: "memory");                       \
    __builtin_amdgcn_sched_barrier(0);                                       \
    __builtin_amdgcn_s_setprio(1);                                           \
    MFMA16(MH, af0, af1, af2, af3)                                           \
    __builtin_amdgcn_s_setprio(0);                                           \
    __builtin_amdgcn_sched_barrier(0);                                       \
    WV                                                                       \
    __builtin_amdgcn_s_barrier();                                            \
  }

__global__ __launch_bounds__(512, 2) void gemm_dn(
    const s16* __restrict__ Abase, const s16* __restrict__ Bbase,
    float* __restrict__ FOut)
{
  constexpr int K  = I_;     // 4096
  constexpr int NB = H_;     // 1024
  constexpr int NT = K / 64;
  constexpr int TN = NB / 256;
  constexpr int TM = C_ / 256;
  constexpr int NWG = TM * TN;

  __shared__ s16 shm[65536];

  const int tid  = threadIdx.x;
  const int wave = tid >> 6, lane = tid & 63;
  const int e    = blockIdx.z;

  const int bid = blockIdx.x;
  const int swz = (bid & 7) * (NWG / 8) + (bid >> 3);
  const int bm = swz / TN, bn = swz % TN;

  const s16* A = Abase + (size_t)e * C_ * K + (size_t)bm * 256 * K;
  const s16* B = Bbase + (size_t)e * NB * K + (size_t)bn * 256 * K;

  const int wm  = (wave >> 2) * 128;
  const int wn  = (wave & 3) * 64;
  const int lr  = lane & 15;
  const int lkb = (lane >> 4) * 8;
  const int xr  = (lr & 7) << 3;
  const int cx0 = lkb ^ xr;
  const int cx1 = (32 + lkb) ^ xr;

  const int srow = tid >> 3;
  const int scol = ((tid & 7) ^ (srow & 7)) * 8;
  const size_t stoff = (size_t)srow * K + scol;
  const int sdst = wave * 512;

  auto stageA = [&](int kt, int b) {
    #pragma unroll
    for (int h = 0; h < 2; ++h)
      #pragma unroll
      for (int ll = 0; ll < 2; ++ll)
        gload16(A + (size_t)(h * 128 + ll * 64) * K + (size_t)kt * 64 + stoff,
                shm + b * 16384 + h * 8192 + ll * 4096 + sdst);
  };
  auto stageB = [&](int kt, int b) {
    #pragma unroll
    for (int h = 0; h < 2; ++h)
      #pragma unroll
      for (int ll = 0; ll < 2; ++ll)
        gload16(B + (size_t)(h * 128 + ll * 64) * K + (size_t)kt * 64 + stoff,
                shm + 32768 + b * 16384 + h * 8192 + ll * 4096 + sdst);
  };

  f32x4 acc[8][4];
  #pragma unroll
  for (int m = 0; m < 8; ++m)
    #pragma unroll
    for (int n = 0; n < 4; ++n) acc[m][n] = (f32x4){0.f, 0.f, 0.f, 0.f};

  stageB(0, 0);
  stageA(0, 0);
  stageB(1, 1);
  VMW4
  __builtin_amdgcn_sched_barrier(0);
  __builtin_amdgcn_s_barrier();

  short8 bf[4];
  for (int i = 0; i < NT / 2; ++i) {
    const int t1 = 2 * i + 1;
    const int t2 = (2 * i + 2 < NT) ? (2 * i + 2) : (NT - 1);
    const int t3 = (2 * i + 3 < NT) ? (2 * i + 3) : (NT - 1);
    PHASE(0, 0, cx0, 1, { stageA(t1, 1); }, )
    PHASE(0, 1, cx0, 0, {}, )
    PHASE(0, 0, cx1, 1, {}, )
    PHASE(0, 1, cx1, 0, { stageB(t2, 0); }, VMW4)
    PHASE(1, 0, cx0, 1, { stageA(t2, 0); }, )
    PHASE(1, 1, cx0, 0, {}, )
    PHASE(1, 0, cx1, 1, {}, )
    PHASE(1, 1, cx1, 0, { stageB(t3, 1); }, VMW4)
  }

  const int lcc = (lane >> 4) * 4;
  float* Op = FOut + (size_t)e * C_ * H_;
  #pragma unroll
  for (int m = 0; m < 8; ++m) {
    const int row = bm * 256 + wm + m * 16 + lr;
    #pragma unroll
    for (int n = 0; n < 4; ++n) {
      const int col = bn * 256 + wn + n * 16 + lcc;
      __builtin_nontemporal_store(acc[m][n],
                                  (float4v*)(Op + (size_t)row * H_ + col));
    }
  }
}

// ---------------------------------------------------------------------------
extern "C" void kernel_launch(void* const* d_in, const int* in_sizes, int n_in,
                              void* d_out, int out_size, void* d_ws, size_t ws_size,
                              hipStream_t stream) {
  const float* x  = (const float*)d_in[0];
  const float* Wg = (const float*)d_in[1];
  const float* Wu = (const float*)d_in[2];
  const float* Wd = (const float*)d_in[3];
  float* out = (float*)d_out;

  const size_t szX  = (size_t)C_ * H_;
  const size_t szGU = (size_t)2 * I_ * H_;
  const size_t szWd = (size_t)H_ * I_;
  const size_t szH  = (size_t)C_ * I_;

  const size_t needFull = 2 * E_ * (szX + szGU + szWd + szH);   // 512 MiB

  if (ws_size >= needFull) {
    s16* xb  = (s16*)d_ws;                  // [E][C][H]
    s16* Wgu = xb  + E_ * szX;              // [E][2I][H] interleaved
    s16* WdT = Wgu + E_ * szGU;             // [E][H][I]
    s16* hbf = WdT + E_ * szWd;             // [E][C][I]

    prep_kernel<<<dim3(1024, E_, 4), 256, 0, stream>>>(
        x, Wg, Wu, Wd, xb, Wgu, WdT);
    gemm_gu<<<dim3((C_/256)*(2*I_/256), 1, E_), 512, 0, stream>>>(
        xb, Wgu, hbf);
    gemm_dn<<<dim3((C_/256)*(H_/256), 1, E_), 512, 0, stream>>>(
        hbf, WdT, out);
  } else {
    // per-expert fallback (67 MiB workspace), same kernels with gridZ=1
    s16* xb  = (s16*)d_ws;
    s16* Wgu = xb  + szX;
    s16* WdT = Wgu + szGU;
    s16* hbf = WdT + szWd;

    for (int e = 0; e < E_; ++e) {
      prep_kernel<<<dim3(1024, 1, 4), 256, 0, stream>>>(
          x + e * szX, Wg + e * szWd, Wu + e * szWd, Wd + e * szWd,
          xb, Wgu, WdT);
      gemm_gu<<<dim3((C_/256)*(2*I_/256), 1, 1), 512, 0, stream>>>(
          xb, Wgu, hbf);
      gemm_dn<<<dim3((C_/256)*(H_/256), 1, 1), 512, 0, stream>>>(
          hbf, WdT, out + e * szX);
    }
  }
}

// Round 9
// 1022.916 us; speedup vs baseline: 5.5029x; 5.5029x over previous
//
#include <hip/hip_runtime.h>
#include <hip/hip_bf16.h>
#include <stdint.h>
#include <stddef.h>

#define E_ 8
#define C_ 4096
#define H_ 1024
#define I_ 4096

typedef short s16;
typedef __attribute__((ext_vector_type(8))) short short8;   // 8 bf16 (4 VGPRs)
typedef __attribute__((ext_vector_type(4))) short short4v;  // 4 bf16 (8B)
typedef __attribute__((ext_vector_type(4))) float f32x4;    // MFMA C/D frag
typedef __attribute__((ext_vector_type(4))) float float4v;

__device__ __forceinline__ s16 f2bf(float f) {
  union { __hip_bfloat16 h; s16 s; } u;
  u.h = __float2bfloat16(f);
  return u.s;
}

// async global->LDS, 16B per lane. LDS dest is wave-uniform base + lane*16.
__device__ __forceinline__ void gload16(const void* gsrc, void* ldst) {
  __builtin_amdgcn_global_load_lds(
      (const __attribute__((address_space(1))) void*)gsrc,
      (__attribute__((address_space(3))) void*)ldst, 16, 0, 0);
}

// ---------------------------------------------------------------------------
// prep: expert = blockIdx.y   (unchanged from r3..r8)
// ---------------------------------------------------------------------------
__global__ __launch_bounds__(256) void prep_kernel(
    const float* __restrict__ x, const float* __restrict__ Wg,
    const float* __restrict__ Wu, const float* __restrict__ Wd,
    s16* __restrict__ xb, s16* __restrict__ Wgu, s16* __restrict__ WdT)
{
  __shared__ float tile[64][65];
  const int t = threadIdx.x;
  const int z = blockIdx.z;
  const size_t e = blockIdx.y;

  if (z == 0) {
    size_t base = e * (size_t)C_ * H_ + ((size_t)blockIdx.x * 256 + t) * 16;
    for (int j = 0; j < 16; j += 8) {
      float4v v0 = *(const float4v*)(x + base + j);
      float4v v1 = *(const float4v*)(x + base + j + 4);
      s16 o[8];
      o[0] = f2bf(v0[0]); o[1] = f2bf(v0[1]); o[2] = f2bf(v0[2]); o[3] = f2bf(v0[3]);
      o[4] = f2bf(v1[0]); o[5] = f2bf(v1[1]); o[6] = f2bf(v1[2]); o[7] = f2bf(v1[3]);
      *(short8*)(xb + base + j) = *(short8*)o;
    }
    return;
  }

  const float* src; int Cc;
  if (z == 1)      { src = Wg + e * (size_t)H_ * I_; Cc = I_; }
  else if (z == 2) { src = Wu + e * (size_t)H_ * I_; Cc = I_; }
  else             { src = Wd + e * (size_t)H_ * I_; Cc = H_; }

  const int tpr  = Cc >> 6;
  const int trow = blockIdx.x / tpr;
  const int tcol = blockIdx.x % tpr;

  const int c = t & 63, rq = t >> 6;
  for (int i = 0; i < 16; ++i) {
    int r = rq * 16 + i;
    tile[r][c] = src[(size_t)(trow * 64 + r) * Cc + tcol * 64 + c];
  }
  __syncthreads();

  const int ro = t >> 2, cb = (t & 3) * 16;
  s16 o[16];
  for (int j = 0; j < 16; ++j) o[j] = f2bf(tile[cb + j][ro]);

  const int i0 = tcol * 64 + ro;   // transposed row index
  s16* op;
  if (z == 3) {
    op = WdT + e * (size_t)H_ * I_ + (size_t)i0 * I_ + trow * 64 + cb;
  } else {
    int grow = ((i0 & ~15) << 1) + (i0 & 15) + ((z == 2) ? 16 : 0);
    op = Wgu + e * (size_t)2 * I_ * H_ + (size_t)grow * H_ + trow * 64 + cb;
  }
  *(short8*)op       = *(short8*)&o[0];
  *(short8*)(op + 8) = *(short8*)&o[8];
}

// ===========================================================================
// Shared MFMA macro (swapped operands -> D^T layout, r7-verified):
// lane holds row = base + m*16 + (lane&15), cols n*16 + (lane>>4)*4 + q.
// ===========================================================================
#define MFMA16(MH, A0, A1, A2, A3)                                                            \
  acc[(MH)*4+0][0] = __builtin_amdgcn_mfma_f32_16x16x32_bf16(bf[0], A0, acc[(MH)*4+0][0],0,0,0); \
  acc[(MH)*4+0][1] = __builtin_amdgcn_mfma_f32_16x16x32_bf16(bf[1], A0, acc[(MH)*4+0][1],0,0,0); \
  acc[(MH)*4+0][2] = __builtin_amdgcn_mfma_f32_16x16x32_bf16(bf[2], A0, acc[(MH)*4+0][2],0,0,0); \
  acc[(MH)*4+0][3] = __builtin_amdgcn_mfma_f32_16x16x32_bf16(bf[3], A0, acc[(MH)*4+0][3],0,0,0); \
  acc[(MH)*4+1][0] = __builtin_amdgcn_mfma_f32_16x16x32_bf16(bf[0], A1, acc[(MH)*4+1][0],0,0,0); \
  acc[(MH)*4+1][1] = __builtin_amdgcn_mfma_f32_16x16x32_bf16(bf[1], A1, acc[(MH)*4+1][1],0,0,0); \
  acc[(MH)*4+1][2] = __builtin_amdgcn_mfma_f32_16x16x32_bf16(bf[2], A1, acc[(MH)*4+1][2],0,0,0); \
  acc[(MH)*4+1][3] = __builtin_amdgcn_mfma_f32_16x16x32_bf16(bf[3], A1, acc[(MH)*4+1][3],0,0,0); \
  acc[(MH)*4+2][0] = __builtin_amdgcn_mfma_f32_16x16x32_bf16(bf[0], A2, acc[(MH)*4+2][0],0,0,0); \
  acc[(MH)*4+2][1] = __builtin_amdgcn_mfma_f32_16x16x32_bf16(bf[1], A2, acc[(MH)*4+2][1],0,0,0); \
  acc[(MH)*4+2][2] = __builtin_amdgcn_mfma_f32_16x16x32_bf16(bf[2], A2, acc[(MH)*4+2][2],0,0,0); \
  acc[(MH)*4+2][3] = __builtin_amdgcn_mfma_f32_16x16x32_bf16(bf[3], A2, acc[(MH)*4+2][3],0,0,0); \
  acc[(MH)*4+3][0] = __builtin_amdgcn_mfma_f32_16x16x32_bf16(bf[0], A3, acc[(MH)*4+3][0],0,0,0); \
  acc[(MH)*4+3][1] = __builtin_amdgcn_mfma_f32_16x16x32_bf16(bf[1], A3, acc[(MH)*4+3][1],0,0,0); \
  acc[(MH)*4+3][2] = __builtin_amdgcn_mfma_f32_16x16x32_bf16(bf[2], A3, acc[(MH)*4+3][2],0,0,0); \
  acc[(MH)*4+3][3] = __builtin_amdgcn_mfma_f32_16x16x32_bf16(bf[3], A3, acc[(MH)*4+3][3],0,0,0);

#define VMW4 asm volatile("s_waitcnt vmcnt(4)" ::: "memory");
#define VMW6 asm volatile("s_waitcnt vmcnt(6)" ::: "memory");

// ===========================================================================
// gemm_gu: gateup. 4-wave block (256 thr), tile 256x128 (waves 2M x 2N,
// per-wave 128x64), BK=32, LDS 48 KiB dbuf -> 2 INDEPENDENT blocks/CU
// (cross-block overlap covers barrier/drain stalls; r8's folded BK=32 LDS
// layout is HW-verified correct & conflict-free; r8's failure was the
// launch_bounds VGPR cap, fixed here: (256,2) -> 256-reg budget, acc ~128
// AGPR + ~110 arch VGPR = fits 2 waves/SIMD).
// Folded layout per 16KB A-tile (logical [256][32] as [128][64]):
//   phys(R,c) = (R>>1)*64 + (((R&1)*32 + c) ^ (((R>>1)&7)<<3))
// K-loop: 2 barriers/K-tile, counted vmcnt(6) (stage-next issued first;
// exactly one 6-load tile-stage in flight; never drain-to-0).
// ===========================================================================
#define LDA32(B, MH, M) \
  (*(const short8*)(shm + (B)*8192 + aBase + (MH)*2048 + (M)*512))
#define LDB32(B, N) \
  (*(const short8*)(shm + 16384 + (B)*4096 + bBase + (N)*512))

__global__ __launch_bounds__(256, 2) void gemm_gu(
    const s16* __restrict__ Abase, const s16* __restrict__ Bbase,
    s16* __restrict__ HOut)
{
  constexpr int K   = H_;          // 1024
  constexpr int NB  = 2 * I_;      // 8192
  constexpr int NT  = K / 32;      // 32 K-tiles

  __shared__ s16 shm[24576];       // 48 KiB: A dbuf [2][8192] | B dbuf [2][4096]

  const int tid  = threadIdx.x;
  const int wave = tid >> 6, lane = tid & 63;
  const int e    = blockIdx.z;

  // XCD mapping: per XCD 8 bn x 16 bm, bn-inner.
  // Working set per XCD: B octet 8 x 256KB = 2MB + A ~2MB = ~4MB = L2.
  const int bid = blockIdx.x;          // 0..1023 per expert
  const int xcd = bid & 7;
  const int idx = bid >> 3;            // 0..127
  const int bn  = xcd * 8 + (idx & 7); // 0..63
  const int bm  = idx >> 3;            // 0..15

  const s16* A = Abase + (size_t)e * C_ * K + (size_t)bm * 256 * K;
  const s16* B = Bbase + (size_t)e * NB * K + (size_t)bn * 128 * K;

  const int wm = (wave >> 1) * 128;    // 0 / 128
  const int wn = (wave & 1) * 64;      // 0 / 64
  const int lr  = lane & 15;
  const int lkb = (lane >> 4) * 8;

  // read-side folded-swizzle constants (r8, HW-verified)
  const int qA    = (((lr & 1) << 5) | lkb) ^ ((lr >> 1) << 3);
  const int aBase = (wm << 5) + ((lr >> 1) << 6) + qA;
  const int bBase = (wn << 5) + ((lr >> 1) << 6) + qA;

  // staging constants (r8, HW-verified): lane l -> phys (.. + l*8), src row rloc/ck
  const int l     = lane;
  const int inner = (((l & 7) ^ (l >> 3)) << 3);
  const int rloc  = ((l >> 3) << 1) | (inner >> 5);
  const int ck    = inner & 31;
  const int sdst  = wave * 512;        // elements

  auto stageA = [&](int kt, int b) {   // 4 insts: 256 rows
    #pragma unroll
    for (int ch = 0; ch < 4; ++ch)
      gload16(A + (size_t)(ch * 64 + wave * 16 + rloc) * K + kt * 32 + ck,
              shm + b * 8192 + ch * 2048 + sdst);
  };
  auto stageB = [&](int kt, int b) {   // 2 insts: 128 rows
    #pragma unroll
    for (int ch = 0; ch < 2; ++ch)
      gload16(B + (size_t)(ch * 64 + wave * 16 + rloc) * K + kt * 32 + ck,
              shm + 16384 + b * 4096 + ch * 2048 + sdst);
  };

  f32x4 acc[8][4];
  #pragma unroll
  for (int m = 0; m < 8; ++m)
    #pragma unroll
    for (int n = 0; n < 4; ++n) acc[m][n] = (f32x4){0.f, 0.f, 0.f, 0.f};

  // prologue: stage tile0 -> b0 (6 loads left in flight; loop's vmcnt(6)
  // at t=0 drains them after issuing tile1's 6).
  stageA(0, 0);
  stageB(0, 0);

  short8 bf[4];
  for (int t = 0; t < NT; ++t) {
    const int b  = t & 1;
    const int tn = (t + 1 < NT) ? (t + 1) : (NT - 1);
    // stage next tile into b^1 (b^1 free: its last readers finished at the
    // previous tile's closing barrier)
    stageA(tn, b ^ 1);
    stageB(tn, b ^ 1);
    VMW6                                   // tile t (buffer b) complete
    __builtin_amdgcn_sched_barrier(0);
    __builtin_amdgcn_s_barrier();          // publish buffer b
    // --- MH0: read B-frags + A-half0, 16 MFMA ---
    bf[0] = LDB32(b, 0); bf[1] = LDB32(b, 1);
    bf[2] = LDB32(b, 2); bf[3] = LDB32(b, 3);
    {
      short8 a0 = LDA32(b, 0, 0), a1 = LDA32(b, 0, 1);
      short8 a2 = LDA32(b, 0, 2), a3 = LDA32(b, 0, 3);
      asm volatile("s_waitcnt lgkmcnt(0)" ::: "memory");
      __builtin_amdgcn_sched_barrier(0);
      __builtin_amdgcn_s_setprio(1);
      MFMA16(0, a0, a1, a2, a3)
    }
    // --- MH1: read A-half1 (bf reused), 16 MFMA ---
    {
      short8 a0 = LDA32(b, 1, 0), a1 = LDA32(b, 1, 1);
      short8 a2 = LDA32(b, 1, 2), a3 = LDA32(b, 1, 3);
      asm volatile("s_waitcnt lgkmcnt(0)" ::: "memory");
      __builtin_amdgcn_sched_barrier(0);
      MFMA16(1, a0, a1, a2, a3)
      __builtin_amdgcn_s_setprio(0);
    }
    __builtin_amdgcn_sched_barrier(0);
    __builtin_amdgcn_s_barrier();          // all reads of b done
  }

  // epilogue (D^T layout, r7-verified): gate/up in adjacent n-frags.
  const int lcc = (lane >> 4) * 4;
  s16* Hp = HOut + (size_t)e * C_ * I_;
  const int ibase = bn * 64 + (wn >> 1);
  #pragma unroll
  for (int m = 0; m < 8; ++m) {
    const int row = bm * 256 + wm + m * 16 + lr;
    #pragma unroll
    for (int p = 0; p < 2; ++p) {
      const int col = ibase + p * 16 + lcc;
      s16 o4[4];
      #pragma unroll
      for (int q = 0; q < 4; ++q) {
        float g = acc[m][2 * p][q], u = acc[m][2 * p + 1][q];
        float sg = 1.0f / (1.0f + __expf(-g));
        o4[q] = f2bf(g * sg * u);
      }
      __builtin_nontemporal_store(*(short4v*)o4,
                                  (short4v*)(Hp + (size_t)row * I_ + col));
    }
  }
}

// ===========================================================================
// gemm_dn: down GEMM — r7 structure FROZEN (control) + nt final stores.
// 256x256 tile, BK=64, 8-phase, 128 KiB LDS, 1 block/CU.
// ===========================================================================
#define LDAF(B, MH, M, CX) \
  (*(const short8*)(shm + (B)*16384 + ((wm + (MH)*64 + (M)*16 + lr) << 6) + (CX)))
#define LDBF(B, N, CX) \
  (*(const short8*)(shm + 32768 + (B)*16384 + ((wn + (N)*16 + lr) << 6) + (CX)))

#define PHASE(B, MH, CX, RDB, STMT, WV)                                      \
  {                                                                          \
    short8 af0 = LDAF(B, MH, 0, CX);                                         \
    short8 af1 = LDAF(B, MH, 1, CX);                                         \
    short8 af2 = LDAF(B, MH, 2, CX);                                         \
    short8 af3 = LDAF(B, MH, 3, CX);                                         \
    if (RDB) {                                                               \
      bf[0] = LDBF(B, 0, CX); bf[1] = LDBF(B, 1, CX);                        \
      bf[2] = LDBF(B, 2, CX); bf[3] = LDBF(B, 3, CX);                        \
    }                                                                        \
    STMT                                                                     \
    __builtin_amdgcn_sched_barrier(0);                                       \
    __builtin_amdgcn_s_barrier();                                            \
    asm volatile("s_waitcnt lgkmcnt(0)" ::: "memory");                       \
    __builtin_amdgcn_sched_barrier(0);                                       \
    __builtin_amdgcn_s_setprio(1);                                           \
    MFMA16(MH, af0, af1, af2, af3)                                           \
    __builtin_amdgcn_s_setprio(0);                                           \
    __builtin_amdgcn_sched_barrier(0);                                       \
    WV                                                                       \
    __builtin_amdgcn_s_barrier();                                            \
  }

__global__ __launch_bounds__(512, 2) void gemm_dn(
    const s16* __restrict__ Abase, const s16* __restrict__ Bbase,
    float* __restrict__ FOut)
{
  constexpr int K  = I_;     // 4096
  constexpr int NB = H_;     // 1024
  constexpr int NT = K / 64;
  constexpr int TN = NB / 256;
  constexpr int TM = C_ / 256;
  constexpr int NWG = TM * TN;

  __shared__ s16 shm[65536];

  const int tid  = threadIdx.x;
  const int wave = tid >> 6, lane = tid & 63;
  const int e    = blockIdx.z;

  const int bid = blockIdx.x;
  const int swz = (bid & 7) * (NWG / 8) + (bid >> 3);
  const int bm = swz / TN, bn = swz % TN;

  const s16* A = Abase + (size_t)e * C_ * K + (size_t)bm * 256 * K;
  const s16* B = Bbase + (size_t)e * NB * K + (size_t)bn * 256 * K;

  const int wm  = (wave >> 2) * 128;
  const int wn  = (wave & 3) * 64;
  const int lr  = lane & 15;
  const int lkb = (lane >> 4) * 8;
  const int xr  = (lr & 7) << 3;
  const int cx0 = lkb ^ xr;
  const int cx1 = (32 + lkb) ^ xr;

  const int srow = tid >> 3;
  const int scol = ((tid & 7) ^ (srow & 7)) * 8;
  const size_t stoff = (size_t)srow * K + scol;
  const int sdst = wave * 512;

  auto stageA = [&](int kt, int b) {
    #pragma unroll
    for (int h = 0; h < 2; ++h)
      #pragma unroll
      for (int ll = 0; ll < 2; ++ll)
        gload16(A + (size_t)(h * 128 + ll * 64) * K + (size_t)kt * 64 + stoff,
                shm + b * 16384 + h * 8192 + ll * 4096 + sdst);
  };
  auto stageB = [&](int kt, int b) {
    #pragma unroll
    for (int h = 0; h < 2; ++h)
      #pragma unroll
      for (int ll = 0; ll < 2; ++ll)
        gload16(B + (size_t)(h * 128 + ll * 64) * K + (size_t)kt * 64 + stoff,
                shm + 32768 + b * 16384 + h * 8192 + ll * 4096 + sdst);
  };

  f32x4 acc[8][4];
  #pragma unroll
  for (int m = 0; m < 8; ++m)
    #pragma unroll
    for (int n = 0; n < 4; ++n) acc[m][n] = (f32x4){0.f, 0.f, 0.f, 0.f};

  stageB(0, 0);
  stageA(0, 0);
  stageB(1, 1);
  VMW4
  __builtin_amdgcn_sched_barrier(0);
  __builtin_amdgcn_s_barrier();

  short8 bf[4];
  for (int i = 0; i < NT / 2; ++i) {
    const int t1 = 2 * i + 1;
    const int t2 = (2 * i + 2 < NT) ? (2 * i + 2) : (NT - 1);
    const int t3 = (2 * i + 3 < NT) ? (2 * i + 3) : (NT - 1);
    PHASE(0, 0, cx0, 1, { stageA(t1, 1); }, )
    PHASE(0, 1, cx0, 0, {}, )
    PHASE(0, 0, cx1, 1, {}, )
    PHASE(0, 1, cx1, 0, { stageB(t2, 0); }, VMW4)
    PHASE(1, 0, cx0, 1, { stageA(t2, 0); }, )
    PHASE(1, 1, cx0, 0, {}, )
    PHASE(1, 0, cx1, 1, {}, )
    PHASE(1, 1, cx1, 0, { stageB(t3, 1); }, VMW4)
  }

  const int lcc = (lane >> 4) * 4;
  float* Op = FOut + (size_t)e * C_ * H_;
  #pragma unroll
  for (int m = 0; m < 8; ++m) {
    const int row = bm * 256 + wm + m * 16 + lr;
    #pragma unroll
    for (int n = 0; n < 4; ++n) {
      const int col = bn * 256 + wn + n * 16 + lcc;
      __builtin_nontemporal_store(acc[m][n],
                                  (float4v*)(Op + (size_t)row * H_ + col));
    }
  }
}

// ---------------------------------------------------------------------------
extern "C" void kernel_launch(void* const* d_in, const int* in_sizes, int n_in,
                              void* d_out, int out_size, void* d_ws, size_t ws_size,
                              hipStream_t stream) {
  const float* x  = (const float*)d_in[0];
  const float* Wg = (const float*)d_in[1];
  const float* Wu = (const float*)d_in[2];
  const float* Wd = (const float*)d_in[3];
  float* out = (float*)d_out;

  const size_t szX  = (size_t)C_ * H_;
  const size_t szGU = (size_t)2 * I_ * H_;
  const size_t szWd = (size_t)H_ * I_;
  const size_t szH  = (size_t)C_ * I_;

  const size_t needFull = 2 * E_ * (szX + szGU + szWd + szH);   // 512 MiB

  // gateup grid: 16 bm x 64 bn = 1024 blocks/expert (256 thr each)
  constexpr int GU_BLK = (C_ / 256) * ((2 * I_) / 128);
  constexpr int DN_BLK = (C_ / 256) * (H_ / 256);

  if (ws_size >= needFull) {
    s16* xb  = (s16*)d_ws;                  // [E][C][H]
    s16* Wgu = xb  + E_ * szX;              // [E][2I][H] interleaved
    s16* WdT = Wgu + E_ * szGU;             // [E][H][I]
    s16* hbf = WdT + E_ * szWd;             // [E][C][I]

    prep_kernel<<<dim3(1024, E_, 4), 256, 0, stream>>>(
        x, Wg, Wu, Wd, xb, Wgu, WdT);
    gemm_gu<<<dim3(GU_BLK, 1, E_), 256, 0, stream>>>(
        xb, Wgu, hbf);
    gemm_dn<<<dim3(DN_BLK, 1, E_), 512, 0, stream>>>(
        hbf, WdT, out);
  } else {
    // per-expert fallback (67 MiB workspace), same kernels with gridZ=1
    s16* xb  = (s16*)d_ws;
    s16* Wgu = xb  + szX;
    s16* WdT = Wgu + szGU;
    s16* hbf = WdT + szWd;

    for (int e = 0; e < E_; ++e) {
      prep_kernel<<<dim3(1024, 1, 4), 256, 0, stream>>>(
          x + e * szX, Wg + e * szWd, Wu + e * szWd, Wd + e * szWd,
          xb, Wgu, WdT);
      gemm_gu<<<dim3(GU_BLK, 1, 1), 256, 0, stream>>>(
          xb, Wgu, hbf);
      gemm_dn<<<dim3(DN_BLK, 1, 1), 512, 0, stream>>>(
          hbf, WdT, out + e * szX);
    }
  }
}